// Round 2
// baseline (71.450 us; speedup 1.0000x reference)
//
#include <hip/hip_runtime.h>

#define NQ 4
#define DIM 16   // 2^NQ

typedef float f32x4 __attribute__((ext_vector_type(4)));

// ---------------- Fast path: L == 1, B % 256 == 0 ----------------
// Product-state algebra: z_q = cos(th_q) cos(x_q) - sin(th_q) cos(phi_q) sin(x_q)
// <Z0> = z1 z2 z3 ; <Z1> = z0 z1 ; <Z2> = z0 z1 z2 ; <Z3> = z0 z1 z2 z3
//
// One sample per thread: f32x4 load is 16B/lane fully lane-contiguous.
// 4KB LDS transpose so the 4 output planes are also written as 16B/lane f32x4.
__global__ __launch_bounds__(256) void qsim_l1_t_kernel(
    const float* __restrict__ inputs,   // [B, 4]
    const float* __restrict__ weights,  // [1, 4, 3]
    float* __restrict__ out,            // [4, B]
    int B)
{
    __shared__ float sm[NQ][256];

    // uniform per-qubit constants (weights are batch-independent)
    float A[NQ], Bc[NQ];
#pragma unroll
    for (int q = 0; q < NQ; q++) {
        const float phi = weights[q * 3 + 0];
        const float th  = weights[q * 3 + 1];
        float sth, cth;  __sincosf(th, &sth, &cth);
        A[q]  = cth;
        Bc[q] = -sth * __cosf(phi);
    }

    const int tid  = threadIdx.x;
    const int base = blockIdx.x * 256;      // first sample of this block
    const int b    = base + tid;            // this thread's sample

    const f32x4 x = __builtin_nontemporal_load(
        reinterpret_cast<const f32x4*>(inputs) + b);
    const float xs[NQ] = {x.x, x.y, x.z, x.w};

    float z[NQ];
#pragma unroll
    for (int q = 0; q < NQ; q++) {
        float sx, cx;
        __sincosf(xs[q], &sx, &cx);
        z[q] = A[q] * cx + Bc[q] * sx;
    }
    const float z01  = z[0] * z[1];
    const float z012 = z01 * z[2];
    sm[0][tid] = z[1] * z[2] * z[3];   // <Z0>
    sm[1][tid] = z01;                  // <Z1>
    sm[2][tid] = z012;                 // <Z2>
    sm[3][tid] = z012 * z[3];          // <Z3>
    __syncthreads();

    // transpose-out: wave w owns plane q=w; 64 lanes store 64 f32x4 = 256 floats
    const int q = tid >> 6;
    const int i = tid & 63;
    const f32x4 v = *reinterpret_cast<const f32x4*>(&sm[q][i * 4]);
    __builtin_nontemporal_store(v,
        reinterpret_cast<f32x4*>(out + (size_t)q * B + base) + i);
}

// ---------------- Secondary fast path: L == 1, B % 4 == 0 (prev best) ----------------
__global__ __launch_bounds__(256) void qsim_l1_kernel(
    const float* __restrict__ inputs,
    const float* __restrict__ weights,
    float* __restrict__ out,
    int B)
{
    float A[NQ], Bc[NQ];
#pragma unroll
    for (int q = 0; q < NQ; q++) {
        const float phi = weights[q * 3 + 0];
        const float th  = weights[q * 3 + 1];
        float sth, cth;  __sincosf(th, &sth, &cth);
        A[q]  = cth;
        Bc[q] = -sth * __cosf(phi);
    }

    const int t = blockIdx.x * blockDim.x + threadIdx.x;   // handles 4 samples
    const int nquad = B >> 2;
    if (t >= nquad) return;

    const float4* in4 = reinterpret_cast<const float4*>(inputs) + (size_t)t * 4;
    float4 o[NQ];

#pragma unroll
    for (int s = 0; s < 4; s++) {
        const float4 x = in4[s];
        const float xs[NQ] = {x.x, x.y, x.z, x.w};
        float z[NQ];
#pragma unroll
        for (int q = 0; q < NQ; q++) {
            float sx, cx;
            __sincosf(xs[q], &sx, &cx);
            z[q] = A[q] * cx + Bc[q] * sx;
        }
        const float z12  = z[1] * z[2];
        const float z01  = z[0] * z[1];
        const float z012 = z01 * z[2];
        const float e0 = z12 * z[3];
        const float e1 = z01;
        const float e2 = z012;
        const float e3 = z012 * z[3];
        if (s == 0) { o[0].x = e0; o[1].x = e1; o[2].x = e2; o[3].x = e3; }
        if (s == 1) { o[0].y = e0; o[1].y = e1; o[2].y = e2; o[3].y = e3; }
        if (s == 2) { o[0].z = e0; o[1].z = e1; o[2].z = e2; o[3].z = e3; }
        if (s == 3) { o[0].w = e0; o[1].w = e1; o[2].w = e2; o[3].w = e3; }
    }

#pragma unroll
    for (int q = 0; q < NQ; q++) {
        reinterpret_cast<float4*>(out + (size_t)q * B)[t] = o[q];
    }
}

// ---------------- General fallback (any L) ----------------
template<int R>
__device__ __forceinline__ void cnot_ring(float (&sr)[DIM], float (&si)[DIM]) {
#pragma unroll
    for (int q = 0; q < NQ; q++) {
        const int tt = (q + R) % NQ;
        const int cs = 1 << (NQ - 1 - q);
        const int ts = 1 << (NQ - 1 - tt);
#pragma unroll
        for (int i = 0; i < DIM; i++) {
            if ((i & cs) && !(i & ts)) {
                const int j = i | ts;
                float tr = sr[i]; sr[i] = sr[j]; sr[j] = tr;
                float ti = si[i]; si[i] = si[j]; si[j] = ti;
            }
        }
    }
}

__global__ __launch_bounds__(256) void qsim_kernel(
    const float* __restrict__ inputs,
    const float* __restrict__ weights,
    float* __restrict__ out,
    int B, int L)
{
    const int b = blockIdx.x * blockDim.x + threadIdx.x;
    if (b >= B) return;

    const float4 x4 = reinterpret_cast<const float4*>(inputs)[b];
    const float xs[NQ] = {x4.x, x4.y, x4.z, x4.w};

    float sr[DIM], si[DIM];
#pragma unroll
    for (int i = 0; i < DIM; i++) { sr[i] = 0.0f; si[i] = 0.0f; }
    sr[0] = 1.0f;

#pragma unroll
    for (int q = 0; q < NQ; q++) {
        float s, c;
        __sincosf(0.5f * xs[q], &s, &c);
        const int st = 1 << (NQ - 1 - q);
#pragma unroll
        for (int i = 0; i < DIM; i++) {
            if (i & st) continue;
            const int j = i | st;
            const float r0 = sr[i], i0 = si[i], r1 = sr[j], i1 = si[j];
            sr[i] = c * r0 - s * r1;  si[i] = c * i0 - s * i1;
            sr[j] = s * r0 + c * r1;  si[j] = s * i0 + c * i1;
        }
    }

    for (int l = 0; l < L; l++) {
        const int r = l % (NQ - 1) + 1;
#pragma unroll
        for (int q = 0; q < NQ; q++) {
            const float phi = weights[(l * NQ + q) * 3 + 0];
            const float th  = weights[(l * NQ + q) * 3 + 1];
            const float om  = weights[(l * NQ + q) * 3 + 2];
            float stg, ctg;  __sincosf(0.5f * th, &stg, &ctg);
            float sp, cp;    __sincosf(0.5f * (phi + om), &sp, &cp);
            float sm, cm;    __sincosf(0.5f * (phi - om), &sm, &cm);
            const float g00r =  cp * ctg, g00i = -sp * ctg;
            const float g01r = -cm * stg, g01i = -sm * stg;
            const float g10r =  cm * stg, g10i = -sm * stg;
            const float g11r =  cp * ctg, g11i =  sp * ctg;
            const int st = 1 << (NQ - 1 - q);
#pragma unroll
            for (int i = 0; i < DIM; i++) {
                if (i & st) continue;
                const int j = i | st;
                const float r0 = sr[i], i0 = si[i], r1 = sr[j], i1 = si[j];
                sr[i] = g00r * r0 - g00i * i0 + g01r * r1 - g01i * i1;
                si[i] = g00r * i0 + g00i * r0 + g01r * i1 + g01i * r1;
                sr[j] = g10r * r0 - g10i * i0 + g11r * r1 - g11i * i1;
                si[j] = g10r * i0 + g10i * r0 + g11r * i1 + g11i * r1;
            }
        }
        switch (r) {
            case 1: cnot_ring<1>(sr, si); break;
            case 2: cnot_ring<2>(sr, si); break;
            default: cnot_ring<3>(sr, si); break;
        }
    }

    float p[DIM];
#pragma unroll
    for (int i = 0; i < DIM; i++) p[i] = sr[i] * sr[i] + si[i] * si[i];
#pragma unroll
    for (int q = 0; q < NQ; q++) {
        const int st = 1 << (NQ - 1 - q);
        float e = 0.0f;
#pragma unroll
        for (int i = 0; i < DIM; i++) e += (i & st) ? -p[i] : p[i];
        out[(size_t)q * B + b] = e;
    }
}

extern "C" void kernel_launch(void* const* d_in, const int* in_sizes, int n_in,
                              void* d_out, int out_size, void* d_ws, size_t ws_size,
                              hipStream_t stream) {
    const float* inputs  = (const float*)d_in[0];
    const float* weights = (const float*)d_in[1];
    float* out = (float*)d_out;
    const int B = in_sizes[0] / NQ;
    const int L = in_sizes[1] / (NQ * 3);
    const int threads = 256;
    if (L == 1 && (B & 255) == 0) {
        // 1 sample/thread, LDS-transposed f32x4 stores: 16B/lane both sides
        const int blocks = B / 256;
        qsim_l1_t_kernel<<<blocks, threads, 0, stream>>>(inputs, weights, out, B);
    } else if (L == 1 && (B & 3) == 0) {
        const int nquad = B >> 2;
        const int blocks = (nquad + threads - 1) / threads;
        qsim_l1_kernel<<<blocks, threads, 0, stream>>>(inputs, weights, out, B);
    } else {
        const int blocks = (B + threads - 1) / threads;
        qsim_kernel<<<blocks, threads, 0, stream>>>(inputs, weights, out, B, L);
    }
}